// Round 9
// baseline (213.722 us; speedup 1.0000x reference)
//
#include <hip/hip_runtime.h>

#define Bq 8
#define Sq 1024
#define Dq 512

typedef __attribute__((ext_vector_type(8))) short bf16x8;
typedef __attribute__((ext_vector_type(4))) float f32x4;

__device__ __forceinline__ unsigned short f2bf(float f) {
  unsigned int u = __float_as_uint(f);
  return (unsigned short)((u + 0x7fffu + ((u >> 16) & 1u)) >> 16);
}
__device__ __forceinline__ float bf2f(unsigned short h) {
  return __uint_as_float(((unsigned int)h) << 16);
}

__device__ __forceinline__ void load_lds16(const unsigned short* g, unsigned short* l) {
  __builtin_amdgcn_global_load_lds(
      (const __attribute__((address_space(1))) unsigned int*)g,
      (__attribute__((address_space(3))) unsigned int*)l, 16, 0, 0);
}

// ---- both weights fp32 -> bf16 in one launch ----
__global__ void convert_w(const float* __restrict__ w1, unsigned short* __restrict__ w1b,
                          const float* __restrict__ w2, unsigned short* __restrict__ w2b) {
  int blk = blockIdx.x;
  const float* src = (blk < 256) ? w1 : w2;
  unsigned short* dst = (blk < 256) ? w1b : w2b;
  int i = ((blk & 255) * 256 + threadIdx.x) * 4;
  float4 v = *(const float4*)(src + i);
  ushort4 o;
  o.x = f2bf(v.x); o.y = f2bf(v.y); o.z = f2bf(v.z); o.w = f2bf(v.w);
  *(ushort4*)(dst + i) = o;
}

// ---- fused inp pass: bf16 cast + transpose + colsum; x=batch -> XCD pin ----
__global__ void prep_inp(const float* __restrict__ inp, unsigned short* __restrict__ inp_bf,
                         unsigned short* __restrict__ inpT, float* __restrict__ colsum) {
  __shared__ unsigned short tile[32][33];
  __shared__ float csum[8][33];
  int b = blockIdx.x;
  int t0 = blockIdx.y * 32, d0 = blockIdx.z * 32;
  int tx = threadIdx.x, ty = threadIdx.y;  // 32 x 8
  const float* src = inp + ((size_t)b * Sq + t0) * Dq + d0;
  unsigned short* dbf = inp_bf + ((size_t)b * Sq + t0) * Dq + d0;
  float part = 0.f;
#pragma unroll
  for (int i = 0; i < 4; ++i) {
    float v = src[(size_t)(ty + i * 8) * Dq + tx];
    unsigned short h = f2bf(v);
    tile[ty + i * 8][tx] = h;
    dbf[(size_t)(ty + i * 8) * Dq + tx] = h;
    part += v;
  }
  csum[ty][tx] = part;
  __syncthreads();
  unsigned short* dst = inpT + (size_t)b * Dq * Sq;
#pragma unroll
  for (int i = 0; i < 4; ++i)
    dst[(size_t)(d0 + ty + i * 8) * Sq + t0 + tx] = tile[tx][ty + i * 8];
  if (ty == 0) {
    float s = 0.f;
#pragma unroll
    for (int i = 0; i < 8; ++i) s += csum[i][tx];
    atomicAdd(&colsum[b * Dq + d0 + tx], s);
  }
}

// ---- fused aspect pass: bf16 cast + exact fp32 fac ----
__global__ void prep_asp(const float* __restrict__ aspect, const float* __restrict__ colsum,
                         const float* __restrict__ lenv, unsigned short* __restrict__ asp_bf,
                         float* __restrict__ fac) {
  int row = blockIdx.x * 4 + (threadIdx.x >> 6);
  int lane = threadIdx.x & 63;
  int b = row >> 10, s = row & 1023;
  const float* a = aspect + (size_t)row * Dq + lane * 8;
  const float* c = colsum + b * Dq + lane * 8;
  float4 a0 = *(const float4*)a, a1 = *(const float4*)(a + 4);
  float4 c0 = *(const float4*)c, c1 = *(const float4*)(c + 4);
  float sum = a0.x * c0.x + a0.y * c0.y + a0.z * c0.z + a0.w * c0.w +
              a1.x * c1.x + a1.y * c1.y + a1.z * c1.z + a1.w * c1.w;
  ushort4 o0; o0.x = f2bf(a0.x); o0.y = f2bf(a0.y); o0.z = f2bf(a0.z); o0.w = f2bf(a0.w);
  ushort4 o1; o1.x = f2bf(a1.x); o1.y = f2bf(a1.y); o1.z = f2bf(a1.z); o1.w = f2bf(a1.w);
  unsigned short* dst = asp_bf + (size_t)row * Dq + lane * 8;
  *(ushort4*)dst = o0;
  *(ushort4*)(dst + 4) = o1;
#pragma unroll
  for (int o = 32; o; o >>= 1) sum += __shfl_xor(sum, o, 64);
  if (lane == 0) {
    float len = lenv[b];
    float scale = sqrtf(len);
    float f = 0.f;
    if (s < (int)len) f = 1.f / (scale * (sum / scale + 1e-4f));
    fac[row] = f;
  }
}

// ---- 64x64 tile, BK=64, dbuf bf16 MFMA GEMM (Gram): C = A*B^T -> bf16 ----
__global__ __launch_bounds__(256, 5) void gemm_gram(
    const unsigned short* __restrict__ Ag, int K, long strideA, long strideO,
    unsigned short* __restrict__ outBf) {
  __shared__ unsigned short sA[2][64 * 64];
  __shared__ unsigned short sB[2][64 * 64];
  int b = blockIdx.x, bm = blockIdx.y, bn = blockIdx.z;
  const unsigned short* Ab = Ag + (size_t)b * strideA + (size_t)bm * 64 * K;
  const unsigned short* Bb = Ag + (size_t)b * strideA + (size_t)bn * 64 * K;
  int tid = threadIdx.x;
  int lane = tid & 63, wave = tid >> 6;
  int wm = (wave >> 1) * 32, wn = (wave & 1) * 32;
  int lr = lane & 15, lq = lane >> 4;
  int x7 = lr & 7;
  int l3 = lane >> 3, l7 = lane & 7;

  int r0 = wave * 16;
  const unsigned short* gA = Ab + (size_t)(r0 + l3) * K + (l7 ^ l3) * 8;
  const unsigned short* gB = Bb + (size_t)(r0 + l3) * K + (l7 ^ l3) * 8;
  int dbase0 = (r0 * 8 + lane) * 8;
  int dbase1 = ((r0 + 8) * 8 + lane) * 8;

  f32x4 acc[2][2] = {};

  auto issue = [&](int buf, int k0) {
    load_lds16(gA + k0, &sA[buf][dbase0]);
    load_lds16(gA + (size_t)8 * K + k0, &sA[buf][dbase1]);
    load_lds16(gB + k0, &sB[buf][dbase0]);
    load_lds16(gB + (size_t)8 * K + k0, &sB[buf][dbase1]);
  };

  const int nk = K >> 6;
  issue(0, 0);
#pragma unroll
  for (int it = 0; it < nk; ++it) {
    int cur = it & 1;
    __syncthreads();
    if (it + 1 < nk) issue(cur ^ 1, (it + 1) << 6);
#pragma unroll
    for (int c = 0; c < 2; ++c) {
      int g = c * 4 + lq;
      bf16x8 a0 = *(const bf16x8*)&sA[cur][((wm + lr) * 8 + (g ^ x7)) * 8];
      bf16x8 a1 = *(const bf16x8*)&sA[cur][((wm + 16 + lr) * 8 + (g ^ x7)) * 8];
      bf16x8 b0 = *(const bf16x8*)&sB[cur][((wn + lr) * 8 + (g ^ x7)) * 8];
      bf16x8 b1 = *(const bf16x8*)&sB[cur][((wn + 16 + lr) * 8 + (g ^ x7)) * 8];
      acc[0][0] = __builtin_amdgcn_mfma_f32_16x16x32_bf16(a0, b0, acc[0][0], 0, 0, 0);
      acc[0][1] = __builtin_amdgcn_mfma_f32_16x16x32_bf16(a0, b1, acc[0][1], 0, 0, 0);
      acc[1][0] = __builtin_amdgcn_mfma_f32_16x16x32_bf16(a1, b0, acc[1][0], 0, 0, 0);
      acc[1][1] = __builtin_amdgcn_mfma_f32_16x16x32_bf16(a1, b1, acc[1][1], 0, 0, 0);
    }
  }

#pragma unroll
  for (int mi = 0; mi < 2; ++mi)
#pragma unroll
    for (int ni = 0; ni < 2; ++ni)
#pragma unroll
      for (int i = 0; i < 4; ++i) {
        int r = bm * 64 + wm + mi * 16 + lq * 4 + i;
        int cc = bn * 64 + wn + ni * 16 + lr;
        outBf[(size_t)b * strideO + (size_t)r * 512 + cc] = f2bf(acc[mi][ni][i]);
      }
}

// ---- MEGA: per 32-row stripe, fused W + FFN1 + FFN2 + row-normalize ----
// 8 waves = 2 M-groups(16 rows) x 4 N-groups(128 cols). B operands (G[b],
// w1, w2) streamed per-lane from L2 (64B/row coalesced, no K-loop barriers).
// ffn round-trips through padded LDS (C-layout -> A-layout); same buffer
// reused for o1. ffn kept in regs (fp32) for the 2*ffn residual. Norm via
// lr-shuffle + tiny cross-wave LDS reduce; writes final output directly.
#define LP 520  // padded LDS row stride (elements): 2-way banks on frag reads

__global__ __launch_bounds__(512, 2) void mega_ffn(
    const unsigned short* __restrict__ aspb, const unsigned short* __restrict__ G,
    const unsigned short* __restrict__ w1b, const unsigned short* __restrict__ w2b,
    const float* __restrict__ b1, const float* __restrict__ b2,
    const float* __restrict__ inp, const float* __restrict__ aspect,
    const float* __restrict__ fac, const float* __restrict__ lenv,
    float* __restrict__ out) {
  __shared__ unsigned short ldsA[32 * LP];
  __shared__ float ssqW[2][4][16];
  int tid = threadIdx.x;
  int lane = tid & 63, wave = tid >> 6;
  int mg = wave >> 2, ng = wave & 3;
  int lr = lane & 15, lq = lane >> 4;
  int r0 = blockIdx.x * 32;
  int b = r0 >> 10;
  int c0 = ng * 128;
  int arow = r0 + mg * 16 + lr;

  bf16x8 af[16];
  f32x4 acc[8];
  f32x4 ffnv[8];

  // ---- phase 0: ffn = fac * (asp @ G^T) + (inp+aspect)*mask ----
#pragma unroll
  for (int j = 0; j < 16; ++j)
    af[j] = *(const bf16x8*)(aspb + (size_t)arow * 512 + j * 32 + lq * 8);
#pragma unroll
  for (int t = 0; t < 8; ++t) acc[t] = (f32x4){0.f, 0.f, 0.f, 0.f};
  const unsigned short* Gb = G + (size_t)b * 512 * 512;
#pragma unroll
  for (int j = 0; j < 16; ++j) {
    bf16x8 bfr[8];
#pragma unroll
    for (int t = 0; t < 8; ++t)
      bfr[t] = *(const bf16x8*)(Gb + (size_t)(c0 + t * 16 + lr) * 512 + j * 32 + lq * 8);
#pragma unroll
    for (int t = 0; t < 8; ++t)
      acc[t] = __builtin_amdgcn_mfma_f32_16x16x32_bf16(af[j], bfr[t], acc[t], 0, 0, 0);
  }
  int len = (int)lenv[b];
  float facv[4];
#pragma unroll
  for (int i = 0; i < 4; ++i) facv[i] = fac[r0 + mg * 16 + lq * 4 + i];
#pragma unroll
  for (int t = 0; t < 8; ++t) {
#pragma unroll
    for (int i = 0; i < 4; ++i) {
      int r = r0 + mg * 16 + lq * 4 + i;
      size_t idx = (size_t)r * 512 + c0 + t * 16 + lr;
      float add = ((r & 1023) < len) ? (inp[idx] + aspect[idx]) : 0.f;
      float v = acc[t][i] * facv[i] + add;
      ffnv[t][i] = v;
      ldsA[(mg * 16 + lq * 4 + i) * LP + c0 + t * 16 + lr] = f2bf(v);
    }
  }
  __syncthreads();  // ffn visible in LDS

  // ---- phase 1: o1 = relu(ffn @ w1^T + b1) ----
#pragma unroll
  for (int j = 0; j < 16; ++j)
    af[j] = *(const bf16x8*)&ldsA[(mg * 16 + lr) * LP + j * 32 + lq * 8];
  __syncthreads();  // all frag reads done before overwrite
#pragma unroll
  for (int t = 0; t < 8; ++t) acc[t] = (f32x4){0.f, 0.f, 0.f, 0.f};
#pragma unroll
  for (int j = 0; j < 16; ++j) {
    bf16x8 bfr[8];
#pragma unroll
    for (int t = 0; t < 8; ++t)
      bfr[t] = *(const bf16x8*)(w1b + (size_t)(c0 + t * 16 + lr) * 512 + j * 32 + lq * 8);
#pragma unroll
    for (int t = 0; t < 8; ++t)
      acc[t] = __builtin_amdgcn_mfma_f32_16x16x32_bf16(af[j], bfr[t], acc[t], 0, 0, 0);
  }
  float biasv[8];
#pragma unroll
  for (int t = 0; t < 8; ++t) biasv[t] = b1[c0 + t * 16 + lr];
#pragma unroll
  for (int t = 0; t < 8; ++t)
#pragma unroll
    for (int i = 0; i < 4; ++i)
      ldsA[(mg * 16 + lq * 4 + i) * LP + c0 + t * 16 + lr] =
          f2bf(fmaxf(acc[t][i] + biasv[t], 0.f));
  __syncthreads();  // o1 visible

  // ---- phase 2: final = 2*ffn + relu(o1 @ w2^T + b2), then row-normalize ----
#pragma unroll
  for (int j = 0; j < 16; ++j)
    af[j] = *(const bf16x8*)&ldsA[(mg * 16 + lr) * LP + j * 32 + lq * 8];
#pragma unroll
  for (int t = 0; t < 8; ++t) acc[t] = (f32x4){0.f, 0.f, 0.f, 0.f};
#pragma unroll
  for (int j = 0; j < 16; ++j) {
    bf16x8 bfr[8];
#pragma unroll
    for (int t = 0; t < 8; ++t)
      bfr[t] = *(const bf16x8*)(w2b + (size_t)(c0 + t * 16 + lr) * 512 + j * 32 + lq * 8);
#pragma unroll
    for (int t = 0; t < 8; ++t)
      acc[t] = __builtin_amdgcn_mfma_f32_16x16x32_bf16(af[j], bfr[t], acc[t], 0, 0, 0);
  }
#pragma unroll
  for (int t = 0; t < 8; ++t) biasv[t] = b2[c0 + t * 16 + lr];
  float ssq[4] = {0.f, 0.f, 0.f, 0.f};
#pragma unroll
  for (int t = 0; t < 8; ++t)
#pragma unroll
    for (int i = 0; i < 4; ++i) {
      float v = 2.f * ffnv[t][i] + fmaxf(acc[t][i] + biasv[t], 0.f);
      ffnv[t][i] = v;  // reuse as 'final'
      ssq[i] += v * v;
    }
#pragma unroll
  for (int off = 1; off < 16; off <<= 1)
#pragma unroll
    for (int i = 0; i < 4; ++i) ssq[i] += __shfl_xor(ssq[i], off, 64);
  if (lr == 0)
#pragma unroll
    for (int i = 0; i < 4; ++i) ssqW[mg][ng][lq * 4 + i] = ssq[i];
  __syncthreads();
  float rn[4];
#pragma unroll
  for (int i = 0; i < 4; ++i) {
    float s = ssqW[mg][0][lq * 4 + i] + ssqW[mg][1][lq * 4 + i] +
              ssqW[mg][2][lq * 4 + i] + ssqW[mg][3][lq * 4 + i];
    rn[i] = 1.f / sqrtf(s);
  }
#pragma unroll
  for (int t = 0; t < 8; ++t)
#pragma unroll
    for (int i = 0; i < 4; ++i) {
      int r = r0 + mg * 16 + lq * 4 + i;
      out[(size_t)r * 512 + c0 + t * 16 + lr] = ffnv[t][i] * rn[i];
    }
}

extern "C" void kernel_launch(void* const* d_in, const int* in_sizes, int n_in,
                              void* d_out, int out_size, void* d_ws, size_t ws_size,
                              hipStream_t stream) {
  const float* inp = (const float*)d_in[0];
  const float* inp_len = (const float*)d_in[1];
  const float* aspect = (const float*)d_in[2];
  const float* w1 = (const float*)d_in[3];
  const float* b1 = (const float*)d_in[4];
  const float* w2 = (const float*)d_in[5];
  const float* b2 = (const float*)d_in[6];
  float* out = (float*)d_out;

  char* W = (char*)d_ws;
  const size_t MB = 1ull << 20;
  unsigned short* inp_bf = (unsigned short*)(W + 0);        // 8 MB  [B][S][D]
  unsigned short* asp_bf = (unsigned short*)(W + 8 * MB);   // 8 MB  [B][S][D]
  unsigned short* inpT   = (unsigned short*)(W + 16 * MB);  // 8 MB  [B][D][S]
  unsigned short* Gm     = (unsigned short*)(W + 24 * MB);  // 4 MB  [B][D][D]
  unsigned short* w1bf   = (unsigned short*)(W + 28 * MB);  // 512 KB
  unsigned short* w2bf   = (unsigned short*)(W + 28 * MB + 512 * 1024);
  float*          colsum = (float*)(W + 29 * MB);           // 16 KB
  float*          fac    = (float*)(W + 29 * MB + 64 * 1024);  // 32 KB

  // prep
  hipMemsetAsync(colsum, 0, Bq * Dq * sizeof(float), stream);
  prep_inp<<<dim3(8, 32, 16), dim3(32, 8), 0, stream>>>(inp, inp_bf, inpT, colsum);
  convert_w<<<512, 256, 0, stream>>>(w1, w1bf, w2, w2bf);
  prep_asp<<<2048, 256, 0, stream>>>(aspect, colsum, inp_len, asp_bf, fac);

  // Gram: G[b] = inpT[b] @ inpT[b]^T   (M=N=512, K=1024, symmetric)
  gemm_gram<<<dim3(8, 8, 8), 256, 0, stream>>>(
      inpT, 1024, (long)Dq * Sq, (long)Dq * Dq, Gm);

  // MEGA: W + FFN1 + FFN2 + norm, 32 rows/block
  mega_ffn<<<256, 512, 0, stream>>>(
      asp_bf, Gm, w1bf, w2bf, b1, b2, inp, aspect, fac, inp_len, out);
}

// Round 10
// 164.866 us; speedup vs baseline: 1.2963x; 1.2963x over previous
//
#include <hip/hip_runtime.h>

#define Bq 8
#define Sq 1024
#define Dq 512

typedef __attribute__((ext_vector_type(8))) short bf16x8;
typedef __attribute__((ext_vector_type(4))) float f32x4;

__device__ __forceinline__ unsigned short f2bf(float f) {
  unsigned int u = __float_as_uint(f);
  return (unsigned short)((u + 0x7fffu + ((u >> 16) & 1u)) >> 16);
}

__device__ __forceinline__ void load_lds16(const unsigned short* g, unsigned short* l) {
  __builtin_amdgcn_global_load_lds(
      (const __attribute__((address_space(1))) unsigned int*)g,
      (__attribute__((address_space(3))) unsigned int*)l, 16, 0, 0);
}

// ---- prep_inp: transpose to inpT (bf16) + RACE-FREE colsum partials ----
// grid (8,32,16), block (32,8). partial[(b*32+tc)*512 + d] owned uniquely.
__global__ void prep_inp(const float* __restrict__ inp, unsigned short* __restrict__ inpT,
                         float* __restrict__ partial) {
  __shared__ unsigned short tile[32][33];
  __shared__ float csum[8][33];
  int b = blockIdx.x;
  int t0 = blockIdx.y * 32, d0 = blockIdx.z * 32;
  int tx = threadIdx.x, ty = threadIdx.y;
  const float* src = inp + ((size_t)b * Sq + t0) * Dq + d0;
  float part = 0.f;
#pragma unroll
  for (int i = 0; i < 4; ++i) {
    float v = src[(size_t)(ty + i * 8) * Dq + tx];
    tile[ty + i * 8][tx] = f2bf(v);
    part += v;
  }
  csum[ty][tx] = part;
  __syncthreads();
  unsigned short* dst = inpT + (size_t)b * Dq * Sq;
#pragma unroll
  for (int i = 0; i < 4; ++i)
    dst[(size_t)(d0 + ty + i * 8) * Sq + t0 + tx] = tile[tx][ty + i * 8];
  if (ty == 0) {
    float s = 0.f;
#pragma unroll
    for (int i = 0; i < 8; ++i) s += csum[i][tx];
    partial[((size_t)b * 32 + blockIdx.y) * Dq + d0 + tx] = s;
  }
}

// ---- prep_asp: bf16 cast + exact fp32 fac (partial-reduce) + w-convert blocks ----
// grid 2560 x 256: blocks <2048 do aspect rows; >=2048 convert w1/w2.
__global__ void prep_asp(const float* __restrict__ aspect, const float* __restrict__ partial,
                         const float* __restrict__ lenv, unsigned short* __restrict__ asp_bf,
                         float* __restrict__ fac,
                         const float* __restrict__ w1, unsigned short* __restrict__ w1b,
                         const float* __restrict__ w2, unsigned short* __restrict__ w2b) {
  int bx = blockIdx.x;
  if (bx >= 2048) {
    int blk = bx - 2048;
    const float* src = (blk < 256) ? w1 : w2;
    unsigned short* dst = (blk < 256) ? w1b : w2b;
    int i = ((blk & 255) * 256 + threadIdx.x) * 4;
    float4 v = *(const float4*)(src + i);
    ushort4 o;
    o.x = f2bf(v.x); o.y = f2bf(v.y); o.z = f2bf(v.z); o.w = f2bf(v.w);
    *(ushort4*)(dst + i) = o;
    return;
  }
  int row = bx * 4 + (threadIdx.x >> 6);
  int lane = threadIdx.x & 63;
  int b = row >> 10, s = row & 1023;
  // exact fp32 colsum slice for this lane (reduce 32 partials)
  float cs[8] = {0.f, 0.f, 0.f, 0.f, 0.f, 0.f, 0.f, 0.f};
  const float* pb = partial + (size_t)b * 32 * Dq + lane * 8;
#pragma unroll
  for (int tc = 0; tc < 32; ++tc) {
    float4 p0 = *(const float4*)(pb + tc * Dq);
    float4 p1 = *(const float4*)(pb + tc * Dq + 4);
    cs[0] += p0.x; cs[1] += p0.y; cs[2] += p0.z; cs[3] += p0.w;
    cs[4] += p1.x; cs[5] += p1.y; cs[6] += p1.z; cs[7] += p1.w;
  }
  const float* a = aspect + (size_t)row * Dq + lane * 8;
  float4 a0 = *(const float4*)a, a1 = *(const float4*)(a + 4);
  float sum = a0.x * cs[0] + a0.y * cs[1] + a0.z * cs[2] + a0.w * cs[3] +
              a1.x * cs[4] + a1.y * cs[5] + a1.z * cs[6] + a1.w * cs[7];
  ushort4 o0; o0.x = f2bf(a0.x); o0.y = f2bf(a0.y); o0.z = f2bf(a0.z); o0.w = f2bf(a0.w);
  ushort4 o1; o1.x = f2bf(a1.x); o1.y = f2bf(a1.y); o1.z = f2bf(a1.z); o1.w = f2bf(a1.w);
  unsigned short* dst = asp_bf + (size_t)row * Dq + lane * 8;
  *(ushort4*)dst = o0;
  *(ushort4*)(dst + 4) = o1;
#pragma unroll
  for (int o = 32; o; o >>= 1) sum += __shfl_xor(sum, o, 64);
  if (lane == 0) {
    float len = lenv[b];
    float scale = sqrtf(len);
    float f = 0.f;
    if (s < (int)len) f = 1.f / (scale * (sum / scale + 1e-4f));
    fac[row] = f;
  }
}

// ---- Gram GEMM (R8 verbatim): G[b] = inpT[b] @ inpT[b]^T -> bf16 ----
__global__ __launch_bounds__(256, 5) void gemm_gram(
    const unsigned short* __restrict__ Ag, int K, long strideA, long strideO,
    unsigned short* __restrict__ outBf) {
  __shared__ unsigned short sA[2][64 * 64];
  __shared__ unsigned short sB[2][64 * 64];
  int b = blockIdx.x, bm = blockIdx.y, bn = blockIdx.z;
  const unsigned short* Ab = Ag + (size_t)b * strideA + (size_t)bm * 64 * K;
  const unsigned short* Bb = Ag + (size_t)b * strideA + (size_t)bn * 64 * K;
  int tid = threadIdx.x;
  int lane = tid & 63, wave = tid >> 6;
  int wm = (wave >> 1) * 32, wn = (wave & 1) * 32;
  int lr = lane & 15, lq = lane >> 4;
  int x7 = lr & 7;
  int l3 = lane >> 3, l7 = lane & 7;

  int r0 = wave * 16;
  const unsigned short* gA = Ab + (size_t)(r0 + l3) * K + (l7 ^ l3) * 8;
  const unsigned short* gB = Bb + (size_t)(r0 + l3) * K + (l7 ^ l3) * 8;
  int dbase0 = (r0 * 8 + lane) * 8;
  int dbase1 = ((r0 + 8) * 8 + lane) * 8;

  f32x4 acc[2][2] = {};

  auto issue = [&](int buf, int k0) {
    load_lds16(gA + k0, &sA[buf][dbase0]);
    load_lds16(gA + (size_t)8 * K + k0, &sA[buf][dbase1]);
    load_lds16(gB + k0, &sB[buf][dbase0]);
    load_lds16(gB + (size_t)8 * K + k0, &sB[buf][dbase1]);
  };

  const int nk = K >> 6;
  issue(0, 0);
#pragma unroll
  for (int it = 0; it < nk; ++it) {
    int cur = it & 1;
    __syncthreads();
    if (it + 1 < nk) issue(cur ^ 1, (it + 1) << 6);
#pragma unroll
    for (int c = 0; c < 2; ++c) {
      int g = c * 4 + lq;
      bf16x8 a0 = *(const bf16x8*)&sA[cur][((wm + lr) * 8 + (g ^ x7)) * 8];
      bf16x8 a1 = *(const bf16x8*)&sA[cur][((wm + 16 + lr) * 8 + (g ^ x7)) * 8];
      bf16x8 b0 = *(const bf16x8*)&sB[cur][((wn + lr) * 8 + (g ^ x7)) * 8];
      bf16x8 b1 = *(const bf16x8*)&sB[cur][((wn + 16 + lr) * 8 + (g ^ x7)) * 8];
      acc[0][0] = __builtin_amdgcn_mfma_f32_16x16x32_bf16(a0, b0, acc[0][0], 0, 0, 0);
      acc[0][1] = __builtin_amdgcn_mfma_f32_16x16x32_bf16(a0, b1, acc[0][1], 0, 0, 0);
      acc[1][0] = __builtin_amdgcn_mfma_f32_16x16x32_bf16(a1, b0, acc[1][0], 0, 0, 0);
      acc[1][1] = __builtin_amdgcn_mfma_f32_16x16x32_bf16(a1, b1, acc[1][1], 0, 0, 0);
    }
  }

#pragma unroll
  for (int mi = 0; mi < 2; ++mi)
#pragma unroll
    for (int ni = 0; ni < 2; ++ni)
#pragma unroll
      for (int i = 0; i < 4; ++i) {
        int r = bm * 64 + wm + mi * 16 + lq * 4 + i;
        int cc = bn * 64 + wn + ni * 16 + lr;
        outBf[(size_t)b * strideO + (size_t)r * 512 + cc] = f2bf(acc[mi][ni][i]);
      }
}

// ---- MEGA: W + FFN1 + FFN2 + norm in one kernel (R9 structure, fixed B-path) ----
// 32 rows/block, 512 thr = 8 waves (2 mg x 4 ng). B operands (G[b], w1, w2)
// staged through double-buffered LDS chunks (32 K each) with coalesced
// global_load_lds: wave w instr i lane l -> n = i*128+w*16+(l>>2), g = l&3,
// LDS granule slot = n*4+g (lane-linear, natural [n][granule] layout).
// A-frags in regs; ffn kept in regs for the residual; norm folded in.
#define LP 520
#define MEGA_SMEM (32 * LP * 2 + 2 * 32768 + 512)

__global__ __launch_bounds__(512, 2) void mega_ffn(
    const unsigned short* __restrict__ aspb, const unsigned short* __restrict__ G,
    const unsigned short* __restrict__ w1b, const unsigned short* __restrict__ w2b,
    const float* __restrict__ b1, const float* __restrict__ b2,
    const float* __restrict__ inp, const float* __restrict__ aspect,
    const float* __restrict__ fac, const float* __restrict__ lenv,
    float* __restrict__ out) {
  extern __shared__ char smem[];
  unsigned short* ldsA = (unsigned short*)smem;                    // 32 x LP bf16
  unsigned short* wbuf = (unsigned short*)(smem + 32 * LP * 2);    // 2 x 16384 bf16
  float* ssqW = (float*)(smem + 32 * LP * 2 + 2 * 32768);          // [2][4][16]
  int tid = threadIdx.x;
  int lane = tid & 63, wave = tid >> 6;
  int mg = wave >> 2, ng = wave & 3;
  int lr = lane & 15, lq = lane >> 4;
  int r0 = blockIdx.x * 32;
  int b = r0 >> 10;
  int c0 = ng * 128;
  int arow = r0 + mg * 16 + lr;

  bf16x8 af[16];
  f32x4 acc[8];
  f32x4 ffnv[8];

  auto stage = [&](int buf, int kc, const unsigned short* Bsrc) {
#pragma unroll
    for (int i = 0; i < 4; ++i) {
      int n = i * 128 + wave * 16 + (lane >> 2);
      load_lds16(Bsrc + (size_t)n * 512 + kc * 32 + (lane & 3) * 8,
                 wbuf + buf * 16384 + (size_t)(i * 512 + wave * 64 + lane) * 8);
    }
  };

  auto gemmPhase = [&](const unsigned short* Bsrc) {
#pragma unroll
    for (int t = 0; t < 8; ++t) acc[t] = (f32x4){0.f, 0.f, 0.f, 0.f};
    stage(0, 0, Bsrc);
#pragma unroll
    for (int kc = 0; kc < 16; ++kc) {
      int cur = kc & 1;
      __syncthreads();
      if (kc < 15) stage(cur ^ 1, kc + 1, Bsrc);
      bf16x8 bfr[8];
#pragma unroll
      for (int t = 0; t < 8; ++t)
        bfr[t] = *(const bf16x8*)&wbuf[cur * 16384 + (size_t)((c0 + t * 16 + lr) * 4 + lq) * 8];
#pragma unroll
      for (int t = 0; t < 8; ++t)
        acc[t] = __builtin_amdgcn_mfma_f32_16x16x32_bf16(af[kc], bfr[t], acc[t], 0, 0, 0);
    }
  };

  // ---- phase 0: ffn = fac * (asp @ G^T) + (inp+aspect)*mask ----
#pragma unroll
  for (int j = 0; j < 16; ++j)
    af[j] = *(const bf16x8*)(aspb + (size_t)arow * 512 + j * 32 + lq * 8);
  gemmPhase(G + (size_t)b * 512 * 512);
  int len = (int)lenv[b];
  float facv[4];
#pragma unroll
  for (int i = 0; i < 4; ++i) facv[i] = fac[r0 + mg * 16 + lq * 4 + i];
#pragma unroll
  for (int t = 0; t < 8; ++t) {
#pragma unroll
    for (int i = 0; i < 4; ++i) {
      int r = r0 + mg * 16 + lq * 4 + i;
      size_t idx = (size_t)r * 512 + c0 + t * 16 + lr;
      float add = ((r & 1023) < len) ? (inp[idx] + aspect[idx]) : 0.f;
      float v = acc[t][i] * facv[i] + add;
      ffnv[t][i] = v;
      ldsA[(mg * 16 + lq * 4 + i) * LP + c0 + t * 16 + lr] = f2bf(v);
    }
  }
  __syncthreads();

  // ---- phase 1: o1 = relu(ffn @ w1^T + b1) ----
#pragma unroll
  for (int j = 0; j < 16; ++j)
    af[j] = *(const bf16x8*)&ldsA[(mg * 16 + lr) * LP + j * 32 + lq * 8];
  __syncthreads();
  gemmPhase(w1b);
  float biasv[8];
#pragma unroll
  for (int t = 0; t < 8; ++t) biasv[t] = b1[c0 + t * 16 + lr];
#pragma unroll
  for (int t = 0; t < 8; ++t)
#pragma unroll
    for (int i = 0; i < 4; ++i)
      ldsA[(mg * 16 + lq * 4 + i) * LP + c0 + t * 16 + lr] =
          f2bf(fmaxf(acc[t][i] + biasv[t], 0.f));
  __syncthreads();

  // ---- phase 2: final = 2*ffn + relu(o1 @ w2^T + b2), then row-normalize ----
#pragma unroll
  for (int j = 0; j < 16; ++j)
    af[j] = *(const bf16x8*)&ldsA[(mg * 16 + lr) * LP + j * 32 + lq * 8];
  __syncthreads();
  gemmPhase(w2b);
#pragma unroll
  for (int t = 0; t < 8; ++t) biasv[t] = b2[c0 + t * 16 + lr];
  float ssq[4] = {0.f, 0.f, 0.f, 0.f};
#pragma unroll
  for (int t = 0; t < 8; ++t)
#pragma unroll
    for (int i = 0; i < 4; ++i) {
      float v = 2.f * ffnv[t][i] + fmaxf(acc[t][i] + biasv[t], 0.f);
      ffnv[t][i] = v;
      ssq[i] += v * v;
    }
#pragma unroll
  for (int off = 1; off < 16; off <<= 1)
#pragma unroll
    for (int i = 0; i < 4; ++i) ssq[i] += __shfl_xor(ssq[i], off, 64);
  if (lr == 0)
#pragma unroll
    for (int i = 0; i < 4; ++i) ssqW[(mg * 4 + ng) * 16 + lq * 4 + i] = ssq[i];
  __syncthreads();
  float rn[4];
#pragma unroll
  for (int i = 0; i < 4; ++i) {
    float s = ssqW[(mg * 4 + 0) * 16 + lq * 4 + i] + ssqW[(mg * 4 + 1) * 16 + lq * 4 + i] +
              ssqW[(mg * 4 + 2) * 16 + lq * 4 + i] + ssqW[(mg * 4 + 3) * 16 + lq * 4 + i];
    rn[i] = 1.f / sqrtf(s);
  }
#pragma unroll
  for (int t = 0; t < 8; ++t)
#pragma unroll
    for (int i = 0; i < 4; ++i) {
      int r = r0 + mg * 16 + lq * 4 + i;
      out[(size_t)r * 512 + c0 + t * 16 + lr] = ffnv[t][i] * rn[i];
    }
}

extern "C" void kernel_launch(void* const* d_in, const int* in_sizes, int n_in,
                              void* d_out, int out_size, void* d_ws, size_t ws_size,
                              hipStream_t stream) {
  const float* inp = (const float*)d_in[0];
  const float* inp_len = (const float*)d_in[1];
  const float* aspect = (const float*)d_in[2];
  const float* w1 = (const float*)d_in[3];
  const float* b1 = (const float*)d_in[4];
  const float* w2 = (const float*)d_in[5];
  const float* b2 = (const float*)d_in[6];
  float* out = (float*)d_out;

  char* W = (char*)d_ws;
  const size_t MB = 1ull << 20;
  unsigned short* asp_bf = (unsigned short*)(W + 0);        // 8 MB  [B][S][D]
  unsigned short* inpT   = (unsigned short*)(W + 8 * MB);   // 8 MB  [B][D][S]
  unsigned short* Gm     = (unsigned short*)(W + 16 * MB);  // 4 MB  [B][D][D]
  unsigned short* w1bf   = (unsigned short*)(W + 20 * MB);  // 512 KB
  unsigned short* w2bf   = (unsigned short*)(W + 20 * MB + 512 * 1024);
  float*          partial= (float*)(W + 21 * MB);           // 512 KB [B][32][D]
  float*          fac    = (float*)(W + 22 * MB);           // 32 KB

  // 1) inp pass: transpose + colsum partials (race-free, no memset needed)
  prep_inp<<<dim3(8, 32, 16), dim3(32, 8), 0, stream>>>(inp, inpT, partial);

  // 2) aspect pass (exact fp32 fac via partial-reduce) + w1/w2 conversion
  prep_asp<<<2560, 256, 0, stream>>>(aspect, partial, inp_len, asp_bf, fac,
                                     w1, w1bf, w2, w2bf);

  // 3) Gram: G[b] = inpT[b] @ inpT[b]^T   (M=N=512, K=1024)
  gemm_gram<<<dim3(8, 8, 8), 256, 0, stream>>>(
      inpT, 1024, (long)Dq * Sq, (long)Dq * Dq, Gm);

  // 4) MEGA: W + FFN1 + FFN2 + norm (32 rows/block, LDS-staged B operands)
  static bool attr_set = [] {
    hipFuncSetAttribute((const void*)mega_ffn,
                        hipFuncAttributeMaxDynamicSharedMemorySize, MEGA_SMEM);
    return true;
  }();
  (void)attr_set;
  hipFuncSetAttribute((const void*)mega_ffn,
                      hipFuncAttributeMaxDynamicSharedMemorySize, MEGA_SMEM);
  mega_ffn<<<256, 512, MEGA_SMEM, stream>>>(
      asp_bf, Gm, w1bf, w2bf, b1, b2, inp, aspect, fac, inp_len, out);
}